// Round 2
// 4486.207 us; speedup vs baseline: 1.3519x; 1.3519x over previous
//
#include <hip/hip_runtime.h>

// CollaborativeExpertsModule — MI355X/gfx950
// Round 6 = round 5 resubmitted (round-5 bench died harness-side with no
// verdict; kernel re-audited: barriers uniform, all addresses in-bounds &
// 16B-aligned, LDS 80KiB fits 2 blocks/CU, staging rotation bijective).
// Pipelined mgemm: double-buffered LDS + register prefetch (issue t+1
// global loads under tile-t MFMA), ONE barrier per K-step, coalesced
// float4 B-transpose staging with rotated k-offset, split-K=2 for the
// 96-block expert_out GEMM and 48-block final GEMM (deterministic
// partials + float4 reduce). Numerics identical to round 4 (split-fp16
// 3-pass logits path, 1-pass fp16 collab path). Workspace layout
// byte-identical (52,461,824 B, proven).
// d_out (float): [final 4096*768 | aux | tk_idx 4096*2].

typedef unsigned short u16;
typedef unsigned int u32;
typedef _Float16 f16;
typedef f16 f16x4 __attribute__((ext_vector_type(4)));
typedef f16 f16x8 __attribute__((ext_vector_type(8)));
typedef float f32x4 __attribute__((ext_vector_type(4)));

__device__ __forceinline__ float b2f(u16 v){
  union { u32 u; float f; } x; x.u = ((u32)v) << 16; return x.f;
}
__device__ __forceinline__ u16 f2b(float f){
  union { float f; u32 u; } x; x.f = f;
  u32 u = x.u;
  if ((u & 0x7fffffffu) > 0x7f800000u) return (u16)0x7fc0;
  return (u16)((u + 0x7fffu + ((u >> 16) & 1u)) >> 16);
}
__device__ __forceinline__ float gelu_f(float x){
  return 0.5f * x * (1.f + erff(x * 0.70710678118654752f));
}

template<int NW>
__device__ __forceinline__ float blockReduceSum(float v, float* red){
  #pragma unroll
  for (int o = 32; o > 0; o >>= 1) v += __shfl_down(v, o, 64);
  const int wv = threadIdx.x >> 6, ln = threadIdx.x & 63;
  __syncthreads();
  if (ln == 0) red[wv] = v;
  __syncthreads();
  float s = 0.f;
  #pragma unroll
  for (int i = 0; i < NW; i++) s += red[i];
  return s;
}

// =====================  MFMA GEMM (pipelined)  =====================
// C[m,n] = epi( sum_k A[m,k]*B[k,n] ), 128x128 tile, BK=32, 256 thr (4 waves),
// wave owns a 64x64 quadrant = 4x4 mfma_f32_16x16x32_f16 tiles.
// AK: 0 = A fp32, 1 = A bf16(u16).  SPLIT: hi/lo 3-pass (AK==0, B fp32).
// BT: B is (N,K) row-major; else (K,N) staged via in-register transpose.
// DUAL: z<zs -> B1/C1 else B2/C2.  SK2: split-K by 2, z = s*zs+e, s-slice
// writes C1 (s=0) / C2 (s=1) partials (no epilogue allowed with SK2+ACT/RES).
// Pipeline: regs hold raw tile t; per iter: convert->LDS[b], barrier,
// issue loads(t+1), ds_read frags[b], MFMA.  dbuf => single barrier is safe:
// writes to buf b at iter t race only with reads of b at iter t-2, which
// precede barrier(t-1) in every wave's program order.
template<int AK, bool SPLIT, bool BT, bool BIAS, int ACT, bool RES, bool DUAL, bool SK2>
__global__ __launch_bounds__(256, 2) void mgemm(
    const void* __restrict__ Ap, int lda, long long strideA,
    const float* __restrict__ B1, const float* __restrict__ B2, int ldb, long long strideB,
    float* __restrict__ C1, float* __restrict__ C2, int ldc, long long strideC,
    const float* __restrict__ bias, const float* __restrict__ resid, int ldr,
    int Kd, int zs)
{
  __shared__ f16 AsH[2][128*40];
  __shared__ f16 BsH[2][128*40];
  __shared__ f16 AsL[SPLIT ? 2 : 1][SPLIT ? 128*40 : 4];
  __shared__ f16 BsL[SPLIT ? 2 : 1][SPLIT ? 128*40 : 4];

  const int tid = threadIdx.x;
  const int m0 = blockIdx.y * 128, n0 = blockIdx.x * 128;
  const int z = blockIdx.z;
  int zi = z, k0 = 0, KL = Kd;
  const float* Bz; float* Cz;
  if constexpr (DUAL){
    if (z < zs){ zi = z;      Bz = B1 + (long long)zi*strideB; Cz = C1 + (long long)zi*strideC; }
    else       { zi = z - zs; Bz = B2 + (long long)zi*strideB; Cz = C2 + (long long)zi*strideC; }
  } else if constexpr (SK2){
    const int s = (z >= zs) ? 1 : 0;
    zi = z - s * zs;
    KL = Kd >> 1; k0 = s * KL;
    Bz = B1 + (long long)zi*strideB + (BT ? (long long)k0 : (long long)k0 * ldb);
    Cz = (s ? C2 : C1) + (long long)zi*strideC;
  } else {
    Bz = B1 + (long long)z*strideB; Cz = C1 + (long long)z*strideC;
  }
  const float* A32 = (const float*)Ap + (AK==0 ? (long long)zi*strideA : 0) + k0;
  const u16*   A16 = (const u16*)Ap   + (AK==1 ? (long long)zi*strideA : 0) + k0;

  const int ln = tid & 63, wv = tid >> 6;
  const int wm = (wv >> 1) * 64, wn = (wv & 1) * 64;
  const int fr = ln & 15, fq = ln >> 4;

  // staging thread maps
  const int rA = tid >> 1, kcA = (tid & 1) * 16;        // A / BT-B: 2 thr per row
  const int nbB = tid & 31, kbB = tid >> 5;             // !BT transpose map
  const int koB = ((kbB << 2) + ((nbB & 3) << 3)) & 31; // rotated k-offset (halfs)

  f32x4 av[4]; uint4 av16[2]; f32x4 bv[4];

  auto loadAB = [&](int kt){
    if constexpr (AK == 0){
      const float* s = A32 + (size_t)(m0 + rA) * lda + kt + kcA;
      av[0] = ((const f32x4*)s)[0]; av[1] = ((const f32x4*)s)[1];
      av[2] = ((const f32x4*)s)[2]; av[3] = ((const f32x4*)s)[3];
    } else {
      const u16* s = A16 + (size_t)(m0 + rA) * lda + kt + kcA;
      av16[0] = ((const uint4*)s)[0]; av16[1] = ((const uint4*)s)[1];
    }
    if constexpr (BT){
      const float* s = Bz + (size_t)(n0 + rA) * ldb + kt + kcA;
      bv[0] = ((const f32x4*)s)[0]; bv[1] = ((const f32x4*)s)[1];
      bv[2] = ((const f32x4*)s)[2]; bv[3] = ((const f32x4*)s)[3];
    } else {
      const float* s = Bz + (size_t)(kt + (kbB << 2)) * ldb + n0 + (nbB << 2);
      bv[0] = *(const f32x4*)(s);
      bv[1] = *(const f32x4*)(s + ldb);
      bv[2] = *(const f32x4*)(s + 2*ldb);
      bv[3] = *(const f32x4*)(s + 3*ldb);
    }
  };

  auto storeAB = [&](int b){
    if constexpr (AK == 0){
      #pragma unroll
      for (int j = 0; j < 4; j++){
        const f32x4 v = av[j];
        f16x4 h;
        #pragma unroll
        for (int c = 0; c < 4; c++) h[c] = (f16)v[c];
        *(f16x4*)&AsH[b][rA*40 + kcA + j*4] = h;
        if constexpr (SPLIT){
          f16x4 l;
          #pragma unroll
          for (int c = 0; c < 4; c++) l[c] = (f16)(v[c] - (float)h[c]);
          *(f16x4*)&AsL[b][rA*40 + kcA + j*4] = l;
        }
      }
    } else {
      #pragma unroll
      for (int j = 0; j < 2; j++){
        const uint4 v = av16[j];
        f16x8 h;
        h[0]=(f16)b2f((u16)(v.x & 0xffff)); h[1]=(f16)b2f((u16)(v.x >> 16));
        h[2]=(f16)b2f((u16)(v.y & 0xffff)); h[3]=(f16)b2f((u16)(v.y >> 16));
        h[4]=(f16)b2f((u16)(v.z & 0xffff)); h[5]=(f16)b2f((u16)(v.z >> 16));
        h[6]=(f16)b2f((u16)(v.w & 0xffff)); h[7]=(f16)b2f((u16)(v.w >> 16));
        *(f16x8*)&AsH[b][rA*40 + kcA + j*8] = h;
      }
    }
    if constexpr (BT){
      #pragma unroll
      for (int j = 0; j < 4; j++){
        const f32x4 v = bv[j];
        f16x4 h;
        #pragma unroll
        for (int c = 0; c < 4; c++) h[c] = (f16)v[c];
        *(f16x4*)&BsH[b][rA*40 + kcA + j*4] = h;
        if constexpr (SPLIT){
          f16x4 l;
          #pragma unroll
          for (int c = 0; c < 4; c++) l[c] = (f16)(v[c] - (float)h[c]);
          *(f16x4*)&BsL[b][rA*40 + kcA + j*4] = l;
        }
      }
    } else {
      #pragma unroll
      for (int c = 0; c < 4; c++){
        const int row = (nbB << 2) + c;
        f16x4 h;
        h[0]=(f16)bv[0][c]; h[1]=(f16)bv[1][c]; h[2]=(f16)bv[2][c]; h[3]=(f16)bv[3][c];
        *(f16x4*)&BsH[b][row*40 + koB] = h;
        if constexpr (SPLIT){
          f16x4 l;
          l[0]=(f16)(bv[0][c]-(float)h[0]); l[1]=(f16)(bv[1][c]-(float)h[1]);
          l[2]=(f16)(bv[2][c]-(float)h[2]); l[3]=(f16)(bv[3][c]-(float)h[3]);
          *(f16x4*)&BsL[b][row*40 + koB] = l;
        }
      }
    }
  };

  f32x4 acc[4][4];
  #pragma unroll
  for (int i = 0; i < 4; i++)
    #pragma unroll
    for (int j = 0; j < 4; j++){ acc[i][j][0]=0.f; acc[i][j][1]=0.f; acc[i][j][2]=0.f; acc[i][j][3]=0.f; }

  int aoff[4], boff[4];
  #pragma unroll
  for (int i = 0; i < 4; i++) aoff[i] = (wm + i*16 + fr)*40 + fq*8;
  #pragma unroll
  for (int j = 0; j < 4; j++){
    const int brow = wn + j*16 + fr;
    boff[j] = brow*40 + (BT ? fq*8 : (((fq + (brow >> 2)) & 3) << 3));
  }

  loadAB(0);
  const int NT = KL >> 5;
  for (int t = 0; t < NT; t++){
    const int b = t & 1;
    storeAB(b);
    __syncthreads();
    if (t + 1 < NT) loadAB((t + 1) << 5);
    f16x8 aH[4], bH[4];
    #pragma unroll
    for (int i = 0; i < 4; i++) aH[i] = *(const f16x8*)&AsH[b][aoff[i]];
    #pragma unroll
    for (int j = 0; j < 4; j++) bH[j] = *(const f16x8*)&BsH[b][boff[j]];
    #pragma unroll
    for (int i = 0; i < 4; i++)
      #pragma unroll
      for (int j = 0; j < 4; j++)
        acc[i][j] = __builtin_amdgcn_mfma_f32_16x16x32_f16(aH[i], bH[j], acc[i][j], 0, 0, 0);
    if constexpr (SPLIT){
      f16x8 aL[4], bL[4];
      #pragma unroll
      for (int i = 0; i < 4; i++) aL[i] = *(const f16x8*)&AsL[b][aoff[i]];
      #pragma unroll
      for (int j = 0; j < 4; j++) bL[j] = *(const f16x8*)&BsL[b][boff[j]];
      #pragma unroll
      for (int i = 0; i < 4; i++)
        #pragma unroll
        for (int j = 0; j < 4; j++){
          acc[i][j] = __builtin_amdgcn_mfma_f32_16x16x32_f16(aH[i], bL[j], acc[i][j], 0, 0, 0);
          acc[i][j] = __builtin_amdgcn_mfma_f32_16x16x32_f16(aL[i], bH[j], acc[i][j], 0, 0, 0);
        }
    }
  }

  // ---- epilogue: C/D layout col=lane&15, row=quad*4+reg (m89-verified) ----
  #pragma unroll
  for (int j = 0; j < 4; j++){
    const int n = n0 + wn + j*16 + fr;
    float bvv = 0.f;
    if constexpr (BIAS) bvv = bias[n];
    #pragma unroll
    for (int i = 0; i < 4; i++){
      #pragma unroll
      for (int r = 0; r < 4; r++){
        const int m = m0 + wm + i*16 + fq*4 + r;
        float v = acc[i][j][r];
        if constexpr (BIAS) v += bvv;
        if constexpr (ACT == 1) v = gelu_f(v);
        if constexpr (RES) v += resid[(size_t)m * ldr + n];
        Cz[(size_t)m * ldc + n] = v;
      }
    }
  }
}

// ---------- elementwise SwiGLU: h = silu(g)*u (float4) ----------
__global__ void silu_k(const float4* __restrict__ g, const float4* __restrict__ u,
                       float4* __restrict__ h, int n4){
  const int i = blockIdx.x * 256 + threadIdx.x;
  if (i < n4){
    const float4 gv = g[i], uv = u[i];
    float4 r;
    r.x = (gv.x / (1.f + expf(-gv.x))) * uv.x;
    r.y = (gv.y / (1.f + expf(-gv.y))) * uv.y;
    r.z = (gv.z / (1.f + expf(-gv.z))) * uv.z;
    r.w = (gv.w / (1.f + expf(-gv.w))) * uv.w;
    h[i] = r;
  }
}

// ---------- dst += src (float4), split-K reduce ----------
__global__ void add_k(float* __restrict__ dst, const float* __restrict__ src, int n4){
  const int i = blockIdx.x * 256 + threadIdx.x;
  if (i < n4){
    const f32x4 a = ((const f32x4*)dst)[i];
    const f32x4 b = ((const f32x4*)src)[i];
    f32x4 c; c[0]=a[0]+b[0]; c[1]=a[1]+b[1]; c[2]=a[2]+b[2]; c[3]=a[3]+b[3];
    ((f32x4*)dst)[i] = c;
  }
}

// ---------- router self-attention over E=8 experts, 12 heads, hd=64 (fp32) ----------
__global__ __launch_bounds__(128) void router_attn(const float* __restrict__ qkv,
                                                   float* __restrict__ attn_o){
  __shared__ float L[8 * 1536];
  __shared__ float Ps[96][8];
  const int t = blockIdx.x, tid = threadIdx.x;
  const float* src = qkv + (size_t)t * 8 * 2304;
  for (int i = tid; i < 3072; i += 128){
    const int e = i / 384, c4 = i - e * 384;
    ((float4*)L)[i] = ((const float4*)(src + (size_t)e * 2304))[c4];
  }
  __syncthreads();
  if (tid < 96){
    const int h = tid >> 3, e = tid & 7;
    const float* q = L + e * 1536 + h * 64;
    float s[8]; float mx = -1e30f;
    #pragma unroll
    for (int e2 = 0; e2 < 8; e2++){
      const float* kk = L + e2 * 1536 + 768 + h * 64;
      float acc = 0.f;
      #pragma unroll
      for (int d = 0; d < 64; d++) acc = fmaf(q[d], kk[d], acc);
      s[e2] = acc * 0.125f;
      mx = fmaxf(mx, s[e2]);
    }
    float den = 0.f;
    #pragma unroll
    for (int e2 = 0; e2 < 8; e2++){ s[e2] = expf(s[e2] - mx); den += s[e2]; }
    const float inv = 1.f / den;
    #pragma unroll
    for (int e2 = 0; e2 < 8; e2++) Ps[tid][e2] = s[e2] * inv;
  }
  __syncthreads();
  for (int i = tid; i < 1536; i += 128){
    const int e = i / 192, c4 = i - e * 192;
    ((float4*)L)[i] = ((const float4*)(src + (size_t)e * 2304 + 1536))[c4];
  }
  __syncthreads();
  if (tid < 96){
    const int h = tid >> 3, e = tid & 7;
    float p[8];
    #pragma unroll
    for (int e2 = 0; e2 < 8; e2++) p[e2] = Ps[tid][e2];
    float* dst = attn_o + ((size_t)t * 8 + e) * 768 + h * 64;
    for (int d = 0; d < 64; d++){
      float acc = 0.f;
      #pragma unroll
      for (int e2 = 0; e2 < 8; e2++) acc = fmaf(p[e2], L[e2 * 768 + h * 64 + d], acc);
      dst[d] = acc;
    }
  }
}

// ---------- router tail (per 256-token chunk) ----------
__global__ __launch_bounds__(256) void router_final(
    const float* __restrict__ proj, const float* __restrict__ eoc,
    const float* __restrict__ rnw, const float* __restrict__ gw,
    int t0, float* __restrict__ usage, float* __restrict__ tkp,
    u16* __restrict__ sf, float* __restrict__ oidx)
{
  const int tl = blockIdx.x, t = t0 + tl, tid = threadIdx.x;
  __shared__ float red[4];
  __shared__ float lg[8];
  __shared__ int sidx[2];
  __shared__ float csum[768];
  for (int i = tid; i < 768; i += 256) csum[i] = 0.f;
  __syncthreads();
  for (int e = 0; e < 8; e++){
    const float* pr = proj + ((size_t)tl * 8 + e) * 768;
    const float* er = eoc  + ((size_t)tl * 8 + e) * 768;
    float v[3]; float ss = 0.f;
    #pragma unroll
    for (int i = 0; i < 3; i++){ const int c = tid + i * 256; v[i] = pr[c] + er[c]; ss += v[i] * v[i]; }
    ss = blockReduceSum<4>(ss, red);
    const float sc = 1.f / sqrtf(ss * (1.f / 768.f) + 1e-5f);
    #pragma unroll
    for (int i = 0; i < 3; i++){ const int c = tid + i * 256; csum[c] += v[i] * sc * rnw[c]; }
  }
  for (int j = 0; j < 8; j++){
    float p = 0.f;
    #pragma unroll
    for (int i = 0; i < 3; i++){ const int c = tid + i * 256; p += csum[c] * gw[j * 768 + c]; }
    p = blockReduceSum<4>(p, red);
    if (tid == 0) lg[j] = p * 0.125f;
  }
  __syncthreads();
  if (tid == 0){
    float mx = -1e30f;
    for (int j = 0; j < 8; j++) mx = fmaxf(mx, lg[j]);
    float ex[8], den = 0.f;
    for (int j = 0; j < 8; j++){ ex[j] = expf(lg[j] - mx); den += ex[j]; }
    const float inv = 1.f / den;
    for (int j = 0; j < 8; j++) atomicAdd(&usage[j], ex[j] * inv);
    int i0 = 0; float l0 = lg[0];
    for (int j = 1; j < 8; j++) if (lg[j] > l0){ l0 = lg[j]; i0 = j; }
    int i1 = -1; float l1 = -1e30f;
    for (int j = 0; j < 8; j++) if (j != i0 && lg[j] > l1){ l1 = lg[j]; i1 = j; }
    const float e1 = expf(l1 - l0);
    const float p0 = 1.f / (1.f + e1);
    tkp[(size_t)t * 2]     = p0;
    tkp[(size_t)t * 2 + 1] = e1 * p0;
    sidx[0] = i0; sidx[1] = i1;
    oidx[(size_t)t * 2]     = (float)i0;
    oidx[(size_t)t * 2 + 1] = (float)i1;
  }
  __syncthreads();
  const int i0 = sidx[0], i1 = sidx[1];
  #pragma unroll
  for (int i = 0; i < 3; i++){
    const int c = tid + i * 256;
    sf[((size_t)t * 2 + 0) * 768 + c] = f2b(eoc[((size_t)tl * 8 + i0) * 768 + c]);
    sf[((size_t)t * 2 + 1) * 768 + c] = f2b(eoc[((size_t)tl * 8 + i1) * 768 + c]);
  }
}

// ---------- collaborative attention: L=2, 2 heads, hd=384 (fp32 io) ----------
__global__ __launch_bounds__(128) void collab_attn(
    const float* __restrict__ qkv, float* __restrict__ attn_o, float* __restrict__ divsum)
{
  const int t = blockIdx.x, tid = threadIdx.x;
  __shared__ float L[4608];
  __shared__ float P[8];
  __shared__ float red[2];
  const float* src = qkv + (size_t)t * 4608;
  for (int i = tid; i < 4608; i += 128) L[i] = src[i];
  __syncthreads();
  for (int hij = 0; hij < 8; hij++){
    const int h = hij >> 2, qi = (hij >> 1) & 1, kj = hij & 1;
    const float* q = L + qi * 2304 + h * 384;
    const float* k = L + kj * 2304 + 768 + h * 384;
    float acc = 0.f;
    for (int d = tid; d < 384; d += 128) acc += q[d] * k[d];
    acc = blockReduceSum<2>(acc, red);
    if (tid == 0) P[hij] = acc;
  }
  __syncthreads();
  if (tid == 0){
    const float scale = 0.051031036307982884f;
    float aw[2][2] = {{0.f,0.f},{0.f,0.f}};
    for (int h = 0; h < 2; h++)
      for (int i = 0; i < 2; i++){
        const float s0 = P[h*4 + i*2 + 0] * scale, s1 = P[h*4 + i*2 + 1] * scale;
        const float m = fmaxf(s0, s1);
        const float e0 = expf(s0 - m), e1 = expf(s1 - m), inv = 1.f / (e0 + e1);
        P[h*4 + i*2 + 0] = e0 * inv; P[h*4 + i*2 + 1] = e1 * inv;
        aw[i][0] += 0.5f * e0 * inv; aw[i][1] += 0.5f * e1 * inv;
      }
    float ent = 0.f;
    for (int i = 0; i < 2; i++)
      for (int j = 0; j < 2; j++) ent -= aw[i][j] * logf(aw[i][j] + 1e-9f);
    atomicAdd(divsum, ent);
  }
  __syncthreads();
  for (int c = tid; c < 768; c += 128){
    const int h = c / 384;
    const float v0 = L[1536 + c], v1 = L[3840 + c];
    attn_o[((size_t)t * 2 + 0) * 768 + c] = P[h*4 + 0] * v0 + P[h*4 + 1] * v1;
    attn_o[((size_t)t * 2 + 1) * 768 + c] = P[h*4 + 2] * v0 + P[h*4 + 3] * v1;
  }
}

// ---------- RMS(a+b)*w -> fp32  (a fp32, b bf16-u16 residual) ----------
__global__ __launch_bounds__(256) void rms_k(const float* __restrict__ a, const u16* __restrict__ b,
                                             const float* __restrict__ wt, float* __restrict__ o){
  const int r = blockIdx.x, tid = threadIdx.x;
  __shared__ float red[4];
  float v[3]; float ss = 0.f;
  #pragma unroll
  for (int i = 0; i < 3; i++){
    const int c = tid + i * 256;
    v[i] = a[(size_t)r * 768 + c] + b2f(b[(size_t)r * 768 + c]);
    ss += v[i] * v[i];
  }
  ss = blockReduceSum<4>(ss, red);
  const float sc = 1.f / sqrtf(ss * (1.f / 768.f) + 1e-5f);
  #pragma unroll
  for (int i = 0; i < 3; i++){
    const int c = tid + i * 256;
    o[(size_t)r * 768 + c] = v[i] * sc * wt[c];
  }
}

// ---------- y[tl] = p0*refined[tl,0] + p1*refined[tl,1]  (quarter-local) ----------
__global__ void wsum(const float* __restrict__ refined, const float* __restrict__ tkp,
                     float* __restrict__ y){
  const int idx = blockIdx.x * 256 + threadIdx.x;   // exactly 1024*768
  const int t = idx / 768, c = idx - t * 768;
  const float r0 = refined[((size_t)t * 2) * 768 + c];
  const float r1 = refined[((size_t)t * 2 + 1) * 768 + c];
  y[idx] = tkp[t * 2] * r0 + tkp[t * 2 + 1] * r1;
}

// ---------- aux ----------
__global__ void aux_k(const float* __restrict__ usage, const float* __restrict__ divsum,
                      float* __restrict__ out){
  if (threadIdx.x == 0 && blockIdx.x == 0){
    float u[8], s = 0.f;
    for (int e = 0; e < 8; e++){ u[e] = usage[e] * (1.f / 4096.f); s += u[e]; }
    const float mean = s * 0.125f;
    float bal = 0.f;
    for (int e = 0; e < 8; e++){ const float d = u[e] - mean; bal += d * d; }
    bal *= 0.125f;
    const float div = divsum[0] * (1.f / 8192.f);
    out[0] = 0.1f * (0.01f * div + 0.01f * bal);
  }
}

__global__ void zero_k(float* p, int n){
  const int i = blockIdx.x * 64 + threadIdx.x;
  if (i < n) p[i] = 0.f;
}

// =====================================================================
extern "C" void kernel_launch(void* const* d_in, const int* in_sizes, int n_in,
                              void* d_out, int out_size, void* d_ws, size_t ws_size,
                              hipStream_t stream)
{
  (void)in_sizes; (void)n_in; (void)out_size; (void)ws_size;
  const float* x       = (const float*)d_in[0];   // (4096, 768)
  const float* w1      = (const float*)d_in[1];   // (8, 768, 2048)
  const float* w3      = (const float*)d_in[2];   // (8, 768, 2048)
  const float* w2      = (const float*)d_in[3];   // (8, 2048, 768)
  const float* r_in_w  = (const float*)d_in[4];   // (2304, 768)
  const float* r_in_b  = (const float*)d_in[5];
  const float* r_out_w = (const float*)d_in[6];   // (768, 768)
  const float* r_out_b = (const float*)d_in[7];
  const float* r_norm_w= (const float*)d_in[8];
  const float* gate_w  = (const float*)d_in[9];   // (8, 768)
  const float* c_in_w  = (const float*)d_in[10];
  const float* c_in_b  = (const float*)d_in[11];
  const float* c_out_w = (const float*)d_in[12];
  const float* c_out_b = (const float*)d_in[13];
  const float* c_norm_w= (const float*)d_in[14];
  const float* ffn_w1  = (const float*)d_in[15];
  const float* ffn_w2  = (const float*)d_in[16];
  const float* o_w     = (const float*)d_in[17];

  // ---- workspace layout (52,461,824 B — identical extent to round 4) ----
  char* wsb   = (char*)d_ws;
  char* arena = wsb;                        // 33,554,432 B, time-shared
  float* eoc  = (float*)(wsb + 33554432);   //  6,291,456 B : chunk expert_out fp32 (256 tok x 8 x 768)
  u16*   sf   = (u16*)  (wsb + 39845888);   // 12,582,912 B : gathered experts bf16 (8192 x 768)
  float* tkp  = (float*)(wsb + 52428800);   //     32,768 B : top-2 probs
  float* usage= (float*)(wsb + 52461568);   //        256 B : usage[8] + divsum at [8]

  // Phase-A aliases (fp32): gate/up first; qkv/attn/proj reuse after w2.
  float* gateb = (float*)(arena);             // 16,777,216 B (8 x 256 x 2048)
  float* upb   = (float*)(arena + 16777216);  // 16,777,216 B
  float* qkvr  = (float*)(arena);             // 18,874,368 B (2048 x 2304)
  float* aor   = (float*)(arena + 18874368);  //  6,291,456 B (2048 x 768)
  float* projr = (float*)(arena + 25165824);  //  6,291,456 B -> 31,457,280 OK

  // Phase-B aliases (fp32, per 1024-token quarter = 2048 rows)
  float* qkvc  = (float*)(arena);             // 18,874,368 B (2048 x 2304)
  float* aoc   = (float*)(arena + 18874368);  //  6,291,456 B
  float* projc = (float*)(arena + 25165824);  //  6,291,456 B -> 31,457,280 OK
  float* aob   = (float*)(arena);             //  6,291,456 B (qkvc dead)
  float* t1b   = (float*)(arena + 6291456);   //  6,291,456 B
  float* refb  = (float*)(arena + 12582912);  //  6,291,456 B -> 18,874,368
  float* ybuf  = (float*)(arena + 18874368);  //  3,145,728 B (aoc dead)

  float* outp    = (float*)d_out;
  float* out_aux = outp + (size_t)4096*768;
  float* out_idx = out_aux + 1;

  zero_k<<<1, 64, 0, stream>>>(usage, 16);

  // -------- Phase A: logits path (split-fp16 MFMA), 16 chunks x 256 tokens ----
  for (int cch = 0; cch < 16; cch++){
    const int t0 = cch * 256;
    // gate & up in one dual dispatch: z<8 -> w1/gateb, z>=8 -> w3/upb
    mgemm<0,true,false,false,0,false,true,false><<<dim3(16,2,16),256,0,stream>>>(
      x + (size_t)t0*768, 768, 0LL,
      w1, w3, 2048, 1572864LL,
      gateb, upb, 2048, 524288LL,
      nullptr, nullptr, 0, 768, 8);
    silu_k<<<4096, 256, 0, stream>>>((const float4*)gateb, (const float4*)upb,
                                     (float4*)gateb, 1048576);
    // expert_out -> eoc rows (tok*8+e), split-K=2: slice0 -> eoc, slice1 -> upb
    mgemm<0,true,false,false,0,false,false,true><<<dim3(6,2,16),256,0,stream>>>(
      gateb, 2048, 524288LL,
      w2, nullptr, 768, 1572864LL,
      eoc, upb, 6144, 768LL,
      nullptr, nullptr, 0, 2048, 8);
    add_k<<<1536, 256, 0, stream>>>(eoc, upb, 393216);
    // router qkv = eoc @ r_in_w^T + b  (2048 rows)
    mgemm<0,true,true,true,0,false,false,false><<<dim3(18,16,1),256,0,stream>>>(
      eoc, 768, 0LL, r_in_w, nullptr, 768, 0LL,
      qkvr, nullptr, 2304, 0LL, r_in_b, nullptr, 0, 768, 0);
    router_attn<<<256, 128, 0, stream>>>(qkvr, aor);
    mgemm<0,true,true,true,0,false,false,false><<<dim3(6,16,1),256,0,stream>>>(
      aor, 768, 0LL, r_out_w, nullptr, 768, 0LL,
      projr, nullptr, 768, 0LL, r_out_b, nullptr, 0, 768, 0);
    router_final<<<256, 256, 0, stream>>>(projr, eoc, r_norm_w, gate_w, t0,
                                          usage, tkp, sf, out_idx);
  }

  // -------- Phase B: collab path (1-pass fp16 MFMA), 4 quarters x 1024 tokens ----
  for (int q = 0; q < 4; q++){
    const int tq0 = q * 1024;
    const u16* sf_q = sf + (size_t)tq0 * 2 * 768;
    mgemm<1,false,true,true,0,false,false,false><<<dim3(18,16,1),256,0,stream>>>(
      sf_q, 768, 0LL, c_in_w, nullptr, 768, 0LL,
      qkvc, nullptr, 2304, 0LL, c_in_b, nullptr, 0, 768, 0);
    collab_attn<<<1024, 128, 0, stream>>>(qkvc, aoc, usage + 8);
    mgemm<0,false,true,true,0,false,false,false><<<dim3(6,16,1),256,0,stream>>>(
      aoc, 768, 0LL, c_out_w, nullptr, 768, 0LL,
      projc, nullptr, 768, 0LL, c_out_b, nullptr, 0, 768, 0);
    rms_k<<<2048, 256, 0, stream>>>(projc, sf_q, c_norm_w, aob);
    // t1 = gelu(ao @ ffn_w1^T)
    mgemm<0,false,true,false,1,false,false,false><<<dim3(6,16,1),256,0,stream>>>(
      aob, 768, 0LL, ffn_w1, nullptr, 768, 0LL,
      t1b, nullptr, 768, 0LL, nullptr, nullptr, 0, 768, 0);
    // refined = t1 @ ffn_w2^T + ao
    mgemm<0,false,true,false,0,true,false,false><<<dim3(6,16,1),256,0,stream>>>(
      t1b, 768, 0LL, ffn_w2, nullptr, 768, 0LL,
      refb, nullptr, 768, 0LL, nullptr, aob, 768, 768, 0);
    wsum<<<3072, 256, 0, stream>>>(refb, tkp + (size_t)tq0 * 2, ybuf);
    // final = y @ o_w^T -> d_out, split-K=2: slice0 -> out, slice1 -> t1b
    mgemm<0,false,true,false,0,false,false,true><<<dim3(6,8,2),256,0,stream>>>(
      ybuf, 768, 0LL, o_w, nullptr, 768, 0LL,
      outp + (size_t)tq0 * 768, t1b, 768, 0LL, nullptr, nullptr, 0, 768, 1);
    add_k<<<768, 256, 0, stream>>>(outp + (size_t)tq0 * 768, t1b, 196608);
  }
  aux_k<<<1, 64, 0, stream>>>(usage, usage + 8, out_aux);
}

// Round 3
// 4209.267 us; speedup vs baseline: 1.4408x; 1.0658x over previous
//
#include <hip/hip_runtime.h>

// CollaborativeExpertsModule — MI355X/gfx950
// Round 7: bank-conflict fix in mgemm staging (all LDS stores now 16B
// ds_write_b128: row-major paths exactly bank-uniform; !BT transpose path
// re-mapped to thread=2rows x 8k with float2 coalesced loads, <=2x uniform
// vs 8-way before). SK2 + fused add2_k epilogue (bias/gelu/residual) for
// the 96-block (6,16) GEMMs -> 192 blocks. router_final rewritten
// wave-per-token (no block barriers, register csum). LDS layout/pitch 40
// and fragment reads unchanged (proven). Numerics: summation-order only.
// Workspace layout byte-identical (52,461,824 B, proven).
// d_out (float): [final 4096*768 | aux | tk_idx 4096*2].

typedef unsigned short u16;
typedef unsigned int u32;
typedef _Float16 f16;
typedef f16 f16x4 __attribute__((ext_vector_type(4)));
typedef f16 f16x8 __attribute__((ext_vector_type(8)));
typedef float f32x4 __attribute__((ext_vector_type(4)));

__device__ __forceinline__ float b2f(u16 v){
  union { u32 u; float f; } x; x.u = ((u32)v) << 16; return x.f;
}
__device__ __forceinline__ u16 f2b(float f){
  union { float f; u32 u; } x; x.f = f;
  u32 u = x.u;
  if ((u & 0x7fffffffu) > 0x7f800000u) return (u16)0x7fc0;
  return (u16)((u + 0x7fffu + ((u >> 16) & 1u)) >> 16);
}
__device__ __forceinline__ float gelu_f(float x){
  return 0.5f * x * (1.f + erff(x * 0.70710678118654752f));
}

template<int NW>
__device__ __forceinline__ float blockReduceSum(float v, float* red){
  #pragma unroll
  for (int o = 32; o > 0; o >>= 1) v += __shfl_down(v, o, 64);
  const int wv = threadIdx.x >> 6, ln = threadIdx.x & 63;
  __syncthreads();
  if (ln == 0) red[wv] = v;
  __syncthreads();
  float s = 0.f;
  #pragma unroll
  for (int i = 0; i < NW; i++) s += red[i];
  return s;
}

__device__ __forceinline__ float waveReduceSum(float v){
  #pragma unroll
  for (int o = 32; o > 0; o >>= 1) v += __shfl_xor(v, o, 64);
  return v;
}

// =====================  MFMA GEMM (pipelined)  =====================
// C[m,n] = epi( sum_k A[m,k]*B[k,n] ), 128x128 tile, BK=32, 256 thr (4 waves),
// wave owns a 64x64 quadrant = 4x4 mfma_f32_16x16x32_f16 tiles.
// AK: 0 = A fp32, 1 = A bf16(u16).  SPLIT: hi/lo 3-pass (AK==0, B fp32).
// BT: B is (N,K) row-major; else (K,N) staged via in-register transpose
//     (thread = 2 n-rows x 8 k's, float2 loads, f16x8 stores; layout
//     block p8 = (kg + (row>>2)) & 3 matches the read un-rotation).
// DUAL: z<zs -> B1/C1 else B2/C2.  SK2: split-K by 2, z = s*zs+e, s-slice
// writes C1 (s=0) / C2 (s=1) partials (epilogue must be in add2_k).
// All LDS staging stores are 16B (b128): row-major paths are bank-uniform
// (8 lanes per 16B slot), transpose path <=2x uniform.
template<int AK, bool SPLIT, bool BT, bool BIAS, int ACT, bool RES, bool DUAL, bool SK2>
__global__ __launch_bounds__(256, 2) void mgemm(
    const void* __restrict__ Ap, int lda, long long strideA,
    const float* __restrict__ B1, const float* __restrict__ B2, int ldb, long long strideB,
    float* __restrict__ C1, float* __restrict__ C2, int ldc, long long strideC,
    const float* __restrict__ bias, const float* __restrict__ resid, int ldr,
    int Kd, int zs)
{
  __shared__ f16 AsH[2][128*40];
  __shared__ f16 BsH[2][128*40];
  __shared__ f16 AsL[SPLIT ? 2 : 1][SPLIT ? 128*40 : 4];
  __shared__ f16 BsL[SPLIT ? 2 : 1][SPLIT ? 128*40 : 4];

  const int tid = threadIdx.x;
  const int m0 = blockIdx.y * 128, n0 = blockIdx.x * 128;
  const int z = blockIdx.z;
  int zi = z, k0 = 0, KL = Kd;
  const float* Bz; float* Cz;
  if constexpr (DUAL){
    if (z < zs){ zi = z;      Bz = B1 + (long long)zi*strideB; Cz = C1 + (long long)zi*strideC; }
    else       { zi = z - zs; Bz = B2 + (long long)zi*strideB; Cz = C2 + (long long)zi*strideC; }
  } else if constexpr (SK2){
    const int s = (z >= zs) ? 1 : 0;
    zi = z - s * zs;
    KL = Kd >> 1; k0 = s * KL;
    Bz = B1 + (long long)zi*strideB + (BT ? (long long)k0 : (long long)k0 * ldb);
    Cz = (s ? C2 : C1) + (long long)zi*strideC;
  } else {
    Bz = B1 + (long long)z*strideB; Cz = C1 + (long long)z*strideC;
  }
  const float* A32 = (const float*)Ap + (AK==0 ? (long long)zi*strideA : 0) + k0;
  const u16*   A16 = (const u16*)Ap   + (AK==1 ? (long long)zi*strideA : 0) + k0;

  const int ln = tid & 63, wv = tid >> 6;
  const int wm = (wv >> 1) * 64, wn = (wv & 1) * 64;
  const int fr = ln & 15, fq = ln >> 4;

  // staging thread maps
  const int rA = tid >> 1, kcA = (tid & 1) * 16;  // A / BT-B: 2 thr per row
  const int npB = tid & 63, kgB = tid >> 6;       // !BT: rows 2npB..+1, k's kgB*8..+7

  f32x4 av[4]; uint4 av16[2]; f32x4 bv[4]; float2 bw[8];

  auto loadAB = [&](int kt){
    if constexpr (AK == 0){
      const float* s = A32 + (size_t)(m0 + rA) * lda + kt + kcA;
      av[0] = ((const f32x4*)s)[0]; av[1] = ((const f32x4*)s)[1];
      av[2] = ((const f32x4*)s)[2]; av[3] = ((const f32x4*)s)[3];
    } else {
      const u16* s = A16 + (size_t)(m0 + rA) * lda + kt + kcA;
      av16[0] = ((const uint4*)s)[0]; av16[1] = ((const uint4*)s)[1];
    }
    if constexpr (BT){
      const float* s = Bz + (size_t)(n0 + rA) * ldb + kt + kcA;
      bv[0] = ((const f32x4*)s)[0]; bv[1] = ((const f32x4*)s)[1];
      bv[2] = ((const f32x4*)s)[2]; bv[3] = ((const f32x4*)s)[3];
    } else {
      const float* s = Bz + (size_t)(kt + kgB * 8) * ldb + n0 + 2 * npB;
      #pragma unroll
      for (int kk = 0; kk < 8; kk++) bw[kk] = *(const float2*)(s + (size_t)kk * ldb);
    }
  };

  auto storeAB = [&](int b){
    if constexpr (AK == 0){
      #pragma unroll
      for (int jj = 0; jj < 2; jj++){
        f16x8 h, l;
        #pragma unroll
        for (int c = 0; c < 8; c++){
          const float v = av[jj*2 + (c>>2)][c & 3];
          h[c] = (f16)v;
          if constexpr (SPLIT) l[c] = (f16)(v - (float)h[c]);
        }
        *(f16x8*)&AsH[b][rA*40 + kcA + jj*8] = h;
        if constexpr (SPLIT) *(f16x8*)&AsL[b][rA*40 + kcA + jj*8] = l;
      }
    } else {
      #pragma unroll
      for (int j = 0; j < 2; j++){
        const uint4 v = av16[j];
        f16x8 h;
        h[0]=(f16)b2f((u16)(v.x & 0xffff)); h[1]=(f16)b2f((u16)(v.x >> 16));
        h[2]=(f16)b2f((u16)(v.y & 0xffff)); h[3]=(f16)b2f((u16)(v.y >> 16));
        h[4]=(f16)b2f((u16)(v.z & 0xffff)); h[5]=(f16)b2f((u16)(v.z >> 16));
        h[6]=(f16)b2f((u16)(v.w & 0xffff)); h[7]=(f16)b2f((u16)(v.w >> 16));
        *(f16x8*)&AsH[b][rA*40 + kcA + j*8] = h;
      }
    }
    if constexpr (BT){
      #pragma unroll
      for (int jj = 0; jj < 2; jj++){
        f16x8 h, l;
        #pragma unroll
        for (int c = 0; c < 8; c++){
          const float v = bv[jj*2 + (c>>2)][c & 3];
          h[c] = (f16)v;
          if constexpr (SPLIT) l[c] = (f16)(v - (float)h[c]);
        }
        *(f16x8*)&BsH[b][rA*40 + kcA + jj*8] = h;
        if constexpr (SPLIT) *(f16x8*)&BsL[b][rA*40 + kcA + jj*8] = l;
      }
    } else {
      #pragma unroll
      for (int c = 0; c < 2; c++){
        const int row = 2*npB + c;
        const int p8 = (kgB + (row >> 2)) & 3;
        f16x8 h, l;
        #pragma unroll
        for (int kk = 0; kk < 8; kk++){
          const float v = c ? bw[kk].y : bw[kk].x;
          h[kk] = (f16)v;
          if constexpr (SPLIT) l[kk] = (f16)(v - (float)h[kk]);
        }
        *(f16x8*)&BsH[b][row*40 + p8*8] = h;
        if constexpr (SPLIT) *(f16x8*)&BsL[b][row*40 + p8*8] = l;
      }
    }
  };

  f32x4 acc[4][4];
  #pragma unroll
  for (int i = 0; i < 4; i++)
    #pragma unroll
    for (int j = 0; j < 4; j++){ acc[i][j][0]=0.f; acc[i][j][1]=0.f; acc[i][j][2]=0.f; acc[i][j][3]=0.f; }

  int aoff[4], boff[4];
  #pragma unroll
  for (int i = 0; i < 4; i++) aoff[i] = (wm + i*16 + fr)*40 + fq*8;
  #pragma unroll
  for (int j = 0; j < 4; j++){
    const int brow = wn + j*16 + fr;
    boff[j] = brow*40 + (BT ? fq*8 : (((fq + (brow >> 2)) & 3) << 3));
  }

  loadAB(0);
  const int NT = KL >> 5;
  for (int t = 0; t < NT; t++){
    const int b = t & 1;
    storeAB(b);
    __syncthreads();
    if (t + 1 < NT) loadAB((t + 1) << 5);
    f16x8 aH[4], bH[4];
    #pragma unroll
    for (int i = 0; i < 4; i++) aH[i] = *(const f16x8*)&AsH[b][aoff[i]];
    #pragma unroll
    for (int j = 0; j < 4; j++) bH[j] = *(const f16x8*)&BsH[b][boff[j]];
    #pragma unroll
    for (int i = 0; i < 4; i++)
      #pragma unroll
      for (int j = 0; j < 4; j++)
        acc[i][j] = __builtin_amdgcn_mfma_f32_16x16x32_f16(aH[i], bH[j], acc[i][j], 0, 0, 0);
    if constexpr (SPLIT){
      f16x8 aL[4], bL[4];
      #pragma unroll
      for (int i = 0; i < 4; i++) aL[i] = *(const f16x8*)&AsL[b][aoff[i]];
      #pragma unroll
      for (int j = 0; j < 4; j++) bL[j] = *(const f16x8*)&BsL[b][boff[j]];
      #pragma unroll
      for (int i = 0; i < 4; i++)
        #pragma unroll
        for (int j = 0; j < 4; j++){
          acc[i][j] = __builtin_amdgcn_mfma_f32_16x16x32_f16(aH[i], bL[j], acc[i][j], 0, 0, 0);
          acc[i][j] = __builtin_amdgcn_mfma_f32_16x16x32_f16(aL[i], bH[j], acc[i][j], 0, 0, 0);
        }
    }
  }

  // ---- epilogue: C/D layout col=lane&15, row=quad*4+reg (m89-verified) ----
  #pragma unroll
  for (int j = 0; j < 4; j++){
    const int n = n0 + wn + j*16 + fr;
    float bvv = 0.f;
    if constexpr (BIAS) bvv = bias[n];
    #pragma unroll
    for (int i = 0; i < 4; i++){
      #pragma unroll
      for (int r = 0; r < 4; r++){
        const int m = m0 + wm + i*16 + fq*4 + r;
        float v = acc[i][j][r];
        if constexpr (BIAS) v += bvv;
        if constexpr (ACT == 1) v = gelu_f(v);
        if constexpr (RES) v += resid[(size_t)m * ldr + n];
        Cz[(size_t)m * ldc + n] = v;
      }
    }
  }
}

// ---------- elementwise SwiGLU: h = silu(g)*u (float4) ----------
__global__ void silu_k(const float4* __restrict__ g, const float4* __restrict__ u,
                       float4* __restrict__ h, int n4){
  const int i = blockIdx.x * 256 + threadIdx.x;
  if (i < n4){
    const float4 gv = g[i], uv = u[i];
    float4 r;
    r.x = (gv.x / (1.f + expf(-gv.x))) * uv.x;
    r.y = (gv.y / (1.f + expf(-gv.y))) * uv.y;
    r.z = (gv.z / (1.f + expf(-gv.z))) * uv.z;
    r.w = (gv.w / (1.f + expf(-gv.w))) * uv.w;
    h[i] = r;
  }
}

// ---------- dst = epi(dst + src [+bias]) [+resid]  (float4), SK2 reduce ----------
template<int ACT, bool RES, bool BIAS>
__global__ void add2_k(float* __restrict__ dst, const float* __restrict__ src,
                       const float* __restrict__ bias, const float* __restrict__ resid,
                       int n4, int ld4){
  const int i = blockIdx.x * 256 + threadIdx.x;
  if (i >= n4) return;
  const f32x4 a = ((const f32x4*)dst)[i];
  const f32x4 b = ((const f32x4*)src)[i];
  const int c4 = (i % ld4) * 4;
  f32x4 r;
  #pragma unroll
  for (int c = 0; c < 4; c++){
    float v = a[c] + b[c];
    if constexpr (BIAS) v += bias[c4 + c];
    if constexpr (ACT == 1) v = gelu_f(v);
    if constexpr (RES) v += resid[(size_t)i * 4 + c];
    r[c] = v;
  }
  ((f32x4*)dst)[i] = r;
}

// ---------- router self-attention over E=8 experts, 12 heads, hd=64 (fp32) ----------
__global__ __launch_bounds__(128) void router_attn(const float* __restrict__ qkv,
                                                   float* __restrict__ attn_o){
  __shared__ float L[8 * 1536];
  __shared__ float Ps[96][8];
  const int t = blockIdx.x, tid = threadIdx.x;
  const float* src = qkv + (size_t)t * 8 * 2304;
  for (int i = tid; i < 3072; i += 128){
    const int e = i / 384, c4 = i - e * 384;
    ((float4*)L)[i] = ((const float4*)(src + (size_t)e * 2304))[c4];
  }
  __syncthreads();
  if (tid < 96){
    const int h = tid >> 3, e = tid & 7;
    const float* q = L + e * 1536 + h * 64;
    float s[8]; float mx = -1e30f;
    #pragma unroll
    for (int e2 = 0; e2 < 8; e2++){
      const float* kk = L + e2 * 1536 + 768 + h * 64;
      float acc = 0.f;
      #pragma unroll
      for (int d = 0; d < 64; d++) acc = fmaf(q[d], kk[d], acc);
      s[e2] = acc * 0.125f;
      mx = fmaxf(mx, s[e2]);
    }
    float den = 0.f;
    #pragma unroll
    for (int e2 = 0; e2 < 8; e2++){ s[e2] = expf(s[e2] - mx); den += s[e2]; }
    const float inv = 1.f / den;
    #pragma unroll
    for (int e2 = 0; e2 < 8; e2++) Ps[tid][e2] = s[e2] * inv;
  }
  __syncthreads();
  for (int i = tid; i < 1536; i += 128){
    const int e = i / 192, c4 = i - e * 192;
    ((float4*)L)[i] = ((const float4*)(src + (size_t)e * 2304 + 1536))[c4];
  }
  __syncthreads();
  if (tid < 96){
    const int h = tid >> 3, e = tid & 7;
    float p[8];
    #pragma unroll
    for (int e2 = 0; e2 < 8; e2++) p[e2] = Ps[tid][e2];
    float* dst = attn_o + ((size_t)t * 8 + e) * 768 + h * 64;
    for (int d = 0; d < 64; d++){
      float acc = 0.f;
      #pragma unroll
      for (int e2 = 0; e2 < 8; e2++) acc = fmaf(p[e2], L[e2 * 768 + h * 64 + d], acc);
      dst[d] = acc;
    }
  }
}

// ---------- router tail, wave-per-token (4 tokens/block, no block barriers) ----------
__global__ __launch_bounds__(256) void router_final(
    const float* __restrict__ proj, const float* __restrict__ eoc,
    const float* __restrict__ rnw, const float* __restrict__ gw,
    int t0, float* __restrict__ usage, float* __restrict__ tkp,
    u16* __restrict__ sf, float* __restrict__ oidx)
{
  const int wv = threadIdx.x >> 6, ln = threadIdx.x & 63;
  const int tl = blockIdx.x * 4 + wv, t = t0 + tl;

  float rw[12];
  #pragma unroll
  for (int g = 0; g < 3; g++){
    const f32x4 w = ((const f32x4*)rnw)[ln + g * 64];
    #pragma unroll
    for (int c = 0; c < 4; c++) rw[g*4 + c] = w[c];
  }

  float cs[12];
  #pragma unroll
  for (int i = 0; i < 12; i++) cs[i] = 0.f;

  for (int e = 0; e < 8; e++){
    const float* pr = proj + ((size_t)tl * 8 + e) * 768;
    const float* er = eoc  + ((size_t)tl * 8 + e) * 768;
    float v[12]; float ss = 0.f;
    #pragma unroll
    for (int g = 0; g < 3; g++){
      const f32x4 a = ((const f32x4*)pr)[ln + g * 64];
      const f32x4 b = ((const f32x4*)er)[ln + g * 64];
      #pragma unroll
      for (int c = 0; c < 4; c++){ const float vv = a[c] + b[c]; v[g*4 + c] = vv; ss += vv * vv; }
    }
    ss = waveReduceSum(ss);
    const float sc = 1.f / sqrtf(ss * (1.f / 768.f) + 1e-5f);
    #pragma unroll
    for (int i = 0; i < 12; i++) cs[i] += v[i] * sc * rw[i];
  }

  float lg[8];
  #pragma unroll
  for (int j = 0; j < 8; j++){
    const float* gwr = gw + j * 768;
    float p = 0.f;
    #pragma unroll
    for (int g = 0; g < 3; g++){
      const f32x4 w = ((const f32x4*)gwr)[ln + g * 64];
      #pragma unroll
      for (int c = 0; c < 4; c++) p += cs[g*4 + c] * w[c];
    }
    lg[j] = waveReduceSum(p) * 0.125f;
  }

  // all lanes hold identical lg[] -> compute top-2 redundantly (uniform)
  int i0 = 0; float l0 = lg[0];
  #pragma unroll
  for (int j = 1; j < 8; j++) if (lg[j] > l0){ l0 = lg[j]; i0 = j; }
  int i1 = -1; float l1 = -1e30f;
  #pragma unroll
  for (int j = 0; j < 8; j++) if (j != i0 && lg[j] > l1){ l1 = lg[j]; i1 = j; }

  if (ln == 0){
    float mx = -1e30f;
    #pragma unroll
    for (int j = 0; j < 8; j++) mx = fmaxf(mx, lg[j]);
    float ex[8], den = 0.f;
    #pragma unroll
    for (int j = 0; j < 8; j++){ ex[j] = expf(lg[j] - mx); den += ex[j]; }
    const float inv = 1.f / den;
    #pragma unroll
    for (int j = 0; j < 8; j++) atomicAdd(&usage[j], ex[j] * inv);
    const float e1 = expf(l1 - l0);
    const float p0 = 1.f / (1.f + e1);
    tkp[(size_t)t * 2]     = p0;
    tkp[(size_t)t * 2 + 1] = e1 * p0;
    oidx[(size_t)t * 2]     = (float)i0;
    oidx[(size_t)t * 2 + 1] = (float)i1;
  }

  // gather selected experts -> bf16 sf rows
  #pragma unroll
  for (int s = 0; s < 2; s++){
    const int ie = s ? i1 : i0;
    const float* er = eoc + ((size_t)tl * 8 + ie) * 768;
    #pragma unroll
    for (int g = 0; g < 3; g++){
      const f32x4 a = ((const f32x4*)er)[ln + g * 64];
      ushort4 o;
      o.x = f2b(a[0]); o.y = f2b(a[1]); o.z = f2b(a[2]); o.w = f2b(a[3]);
      *(ushort4*)&sf[((size_t)t * 2 + s) * 768 + 4 * (ln + g * 64)] = o;
    }
  }
}

// ---------- collaborative attention: L=2, 2 heads, hd=384 (fp32 io) ----------
__global__ __launch_bounds__(128) void collab_attn(
    const float* __restrict__ qkv, float* __restrict__ attn_o, float* __restrict__ divsum)
{
  const int t = blockIdx.x, tid = threadIdx.x;
  __shared__ float L[4608];
  __shared__ float P[8];
  __shared__ float red[2];
  const float* src = qkv + (size_t)t * 4608;
  for (int i = tid; i < 4608; i += 128) L[i] = src[i];
  __syncthreads();
  for (int hij = 0; hij < 8; hij++){
    const int h = hij >> 2, qi = (hij >> 1) & 1, kj = hij & 1;
    const float* q = L + qi * 2304 + h * 384;
    const float* k = L + kj * 2304 + 768 + h * 384;
    float acc = 0.f;
    for (int d = tid; d < 384; d += 128) acc += q[d] * k[d];
    acc = blockReduceSum<2>(acc, red);
    if (tid == 0) P[hij] = acc;
  }
  __syncthreads();
  if (tid == 0){
    const float scale = 0.051031036307982884f;
    float aw[2][2] = {{0.f,0.f},{0.f,0.f}};
    for (int h = 0; h < 2; h++)
      for (int i = 0; i < 2; i++){
        const float s0 = P[h*4 + i*2 + 0] * scale, s1 = P[h*4 + i*2 + 1] * scale;
        const float m = fmaxf(s0, s1);
        const float e0 = expf(s0 - m), e1 = expf(s1 - m), inv = 1.f / (e0 + e1);
        P[h*4 + i*2 + 0] = e0 * inv; P[h*4 + i*2 + 1] = e1 * inv;
        aw[i][0] += 0.5f * e0 * inv; aw[i][1] += 0.5f * e1 * inv;
      }
    float ent = 0.f;
    for (int i = 0; i < 2; i++)
      for (int j = 0; j < 2; j++) ent -= aw[i][j] * logf(aw[i][j] + 1e-9f);
    atomicAdd(divsum, ent);
  }
  __syncthreads();
  for (int c = tid; c < 768; c += 128){
    const int h = c / 384;
    const float v0 = L[1536 + c], v1 = L[3840 + c];
    attn_o[((size_t)t * 2 + 0) * 768 + c] = P[h*4 + 0] * v0 + P[h*4 + 1] * v1;
    attn_o[((size_t)t * 2 + 1) * 768 + c] = P[h*4 + 2] * v0 + P[h*4 + 3] * v1;
  }
}

// ---------- RMS(a+b)*w -> fp32  (a fp32, b bf16-u16 residual) ----------
__global__ __launch_bounds__(256) void rms_k(const float* __restrict__ a, const u16* __restrict__ b,
                                             const float* __restrict__ wt, float* __restrict__ o){
  const int r = blockIdx.x, tid = threadIdx.x;
  __shared__ float red[4];
  float v[3]; float ss = 0.f;
  #pragma unroll
  for (int i = 0; i < 3; i++){
    const int c = tid + i * 256;
    v[i] = a[(size_t)r * 768 + c] + b2f(b[(size_t)r * 768 + c]);
    ss += v[i] * v[i];
  }
  ss = blockReduceSum<4>(ss, red);
  const float sc = 1.f / sqrtf(ss * (1.f / 768.f) + 1e-5f);
  #pragma unroll
  for (int i = 0; i < 3; i++){
    const int c = tid + i * 256;
    o[(size_t)r * 768 + c] = v[i] * sc * wt[c];
  }
}

// ---------- y[tl] = p0*refined[tl,0] + p1*refined[tl,1]  (quarter-local) ----------
__global__ void wsum(const float* __restrict__ refined, const float* __restrict__ tkp,
                     float* __restrict__ y){
  const int idx = blockIdx.x * 256 + threadIdx.x;   // exactly 1024*768
  const int t = idx / 768, c = idx - t * 768;
  const float r0 = refined[((size_t)t * 2) * 768 + c];
  const float r1 = refined[((size_t)t * 2 + 1) * 768 + c];
  y[idx] = tkp[t * 2] * r0 + tkp[t * 2 + 1] * r1;
}

// ---------- aux ----------
__global__ void aux_k(const float* __restrict__ usage, const float* __restrict__ divsum,
                      float* __restrict__ out){
  if (threadIdx.x == 0 && blockIdx.x == 0){
    float u[8], s = 0.f;
    for (int e = 0; e < 8; e++){ u[e] = usage[e] * (1.f / 4096.f); s += u[e]; }
    const float mean = s * 0.125f;
    float bal = 0.f;
    for (int e = 0; e < 8; e++){ const float d = u[e] - mean; bal += d * d; }
    bal *= 0.125f;
    const float div = divsum[0] * (1.f / 8192.f);
    out[0] = 0.1f * (0.01f * div + 0.01f * bal);
  }
}

__global__ void zero_k(float* p, int n){
  const int i = blockIdx.x * 64 + threadIdx.x;
  if (i < n) p[i] = 0.f;
}

// =====================================================================
extern "C" void kernel_launch(void* const* d_in, const int* in_sizes, int n_in,
                              void* d_out, int out_size, void* d_ws, size_t ws_size,
                              hipStream_t stream)
{
  (void)in_sizes; (void)n_in; (void)out_size; (void)ws_size;
  const float* x       = (const float*)d_in[0];   // (4096, 768)
  const float* w1      = (const float*)d_in[1];   // (8, 768, 2048)
  const float* w3      = (const float*)d_in[2];   // (8, 768, 2048)
  const float* w2      = (const float*)d_in[3];   // (8, 2048, 768)
  const float* r_in_w  = (const float*)d_in[4];   // (2304, 768)
  const float* r_in_b  = (const float*)d_in[5];
  const float* r_out_w = (const float*)d_in[6];   // (768, 768)
  const float* r_out_b = (const float*)d_in[7];
  const float* r_norm_w= (const float*)d_in[8];
  const float* gate_w  = (const float*)d_in[9];   // (8, 768)
  const float* c_in_w  = (const float*)d_in[10];
  const float* c_in_b  = (const float*)d_in[11];
  const float* c_out_w = (const float*)d_in[12];
  const float* c_out_b = (const float*)d_in[13];
  const float* c_norm_w= (const float*)d_in[14];
  const float* ffn_w1  = (const float*)d_in[15];
  const float* ffn_w2  = (const float*)d_in[16];
  const float* o_w     = (const float*)d_in[17];

  // ---- workspace layout (52,461,824 B — identical extent to round 4) ----
  char* wsb   = (char*)d_ws;
  char* arena = wsb;                        // 33,554,432 B, time-shared
  float* eoc  = (float*)(wsb + 33554432);   //  6,291,456 B : chunk expert_out fp32 (256 tok x 8 x 768)
  u16*   sf   = (u16*)  (wsb + 39845888);   // 12,582,912 B : gathered experts bf16 (8192 x 768)
  float* tkp  = (float*)(wsb + 52428800);   //     32,768 B : top-2 probs
  float* usage= (float*)(wsb + 52461568);   //        256 B : usage[8] + divsum at [8]

  // Phase-A aliases (fp32): gate/up first; qkv/attn/proj reuse after w2.
  float* gateb = (float*)(arena);             // 16,777,216 B (8 x 256 x 2048)
  float* upb   = (float*)(arena + 16777216);  // 16,777,216 B
  float* qkvr  = (float*)(arena);             // 18,874,368 B (2048 x 2304)
  float* aor   = (float*)(arena + 18874368);  //  6,291,456 B (2048 x 768)
  float* projr = (float*)(arena + 25165824);  //  6,291,456 B -> 31,457,280 OK

  // Phase-B aliases (fp32, per 1024-token quarter = 2048 rows)
  float* qkvc  = (float*)(arena);             // 18,874,368 B (2048 x 2304)
  float* aoc   = (float*)(arena + 18874368);  //  6,291,456 B
  float* projc = (float*)(arena + 25165824);  //  6,291,456 B -> 31,457,280 OK
  float* aob   = (float*)(arena);             //  6,291,456 B (qkvc dead)
  float* t1b   = (float*)(arena + 6291456);   //  6,291,456 B
  float* refb  = (float*)(arena + 12582912);  //  6,291,456 B -> 18,874,368
  float* ybuf  = (float*)(arena + 18874368);  //  3,145,728 B (aoc dead)

  float* outp    = (float*)d_out;
  float* out_aux = outp + (size_t)4096*768;
  float* out_idx = out_aux + 1;

  zero_k<<<1, 64, 0, stream>>>(usage, 16);

  // -------- Phase A: logits path (split-fp16 MFMA), 16 chunks x 256 tokens ----
  for (int cch = 0; cch < 16; cch++){
    const int t0 = cch * 256;
    // gate & up in one dual dispatch: z<8 -> w1/gateb, z>=8 -> w3/upb
    mgemm<0,true,false,false,0,false,true,false><<<dim3(16,2,16),256,0,stream>>>(
      x + (size_t)t0*768, 768, 0LL,
      w1, w3, 2048, 1572864LL,
      gateb, upb, 2048, 524288LL,
      nullptr, nullptr, 0, 768, 8);
    silu_k<<<4096, 256, 0, stream>>>((const float4*)gateb, (const float4*)upb,
                                     (float4*)gateb, 1048576);
    // expert_out -> eoc rows (tok*8+e), split-K=2: slice0 -> eoc, slice1 -> upb
    mgemm<0,true,false,false,0,false,false,true><<<dim3(6,2,16),256,0,stream>>>(
      gateb, 2048, 524288LL,
      w2, nullptr, 768, 1572864LL,
      eoc, upb, 6144, 768LL,
      nullptr, nullptr, 0, 2048, 8);
    add2_k<0,false,false><<<1536, 256, 0, stream>>>(eoc, upb, nullptr, nullptr, 393216, 192);
    // router qkv = eoc @ r_in_w^T + b  (2048 rows)
    mgemm<0,true,true,true,0,false,false,false><<<dim3(18,16,1),256,0,stream>>>(
      eoc, 768, 0LL, r_in_w, nullptr, 768, 0LL,
      qkvr, nullptr, 2304, 0LL, r_in_b, nullptr, 0, 768, 0);
    router_attn<<<256, 128, 0, stream>>>(qkvr, aor);
    // proj = aor @ r_out_w^T (+bias in add2), split-K=2: p0 -> projr, p1 -> qkvr
    mgemm<0,true,true,false,0,false,false,true><<<dim3(6,16,2),256,0,stream>>>(
      aor, 768, 0LL, r_out_w, nullptr, 768, 0LL,
      projr, qkvr, 768, 0LL, nullptr, nullptr, 0, 768, 1);
    add2_k<0,false,true><<<1536, 256, 0, stream>>>(projr, qkvr, r_out_b, nullptr, 393216, 192);
    router_final<<<64, 256, 0, stream>>>(projr, eoc, r_norm_w, gate_w, t0,
                                         usage, tkp, sf, out_idx);
  }

  // -------- Phase B: collab path (1-pass fp16 MFMA), 4 quarters x 1024 tokens ----
  for (int q = 0; q < 4; q++){
    const int tq0 = q * 1024;
    const u16* sf_q = sf + (size_t)tq0 * 2 * 768;
    mgemm<1,false,true,true,0,false,false,false><<<dim3(18,16,1),256,0,stream>>>(
      sf_q, 768, 0LL, c_in_w, nullptr, 768, 0LL,
      qkvc, nullptr, 2304, 0LL, c_in_b, nullptr, 0, 768, 0);
    collab_attn<<<1024, 128, 0, stream>>>(qkvc, aoc, usage + 8);
    // proj = aoc @ c_out_w^T (+bias in add2), SK2: p0 -> projc, p1 -> qkvc
    mgemm<0,false,true,false,0,false,false,true><<<dim3(6,16,2),256,0,stream>>>(
      aoc, 768, 0LL, c_out_w, nullptr, 768, 0LL,
      projc, qkvc, 768, 0LL, nullptr, nullptr, 0, 768, 1);
    add2_k<0,false,true><<<1536, 256, 0, stream>>>(projc, qkvc, c_out_b, nullptr, 393216, 192);
    rms_k<<<2048, 256, 0, stream>>>(projc, sf_q, c_norm_w, aob);
    // t1 = gelu(ao @ ffn_w1^T), SK2: p0 -> t1b, p1 -> refb, gelu in add2
    mgemm<0,false,true,false,0,false,false,true><<<dim3(6,16,2),256,0,stream>>>(
      aob, 768, 0LL, ffn_w1, nullptr, 768, 0LL,
      t1b, refb, 768, 0LL, nullptr, nullptr, 0, 768, 1);
    add2_k<1,false,false><<<1536, 256, 0, stream>>>(t1b, refb, nullptr, nullptr, 393216, 192);
    // refined = t1 @ ffn_w2^T + ao, SK2: p0 -> refb, p1 -> projc, resid in add2
    mgemm<0,false,true,false,0,false,false,true><<<dim3(6,16,2),256,0,stream>>>(
      t1b, 768, 0LL, ffn_w2, nullptr, 768, 0LL,
      refb, projc, 768, 0LL, nullptr, nullptr, 0, 768, 1);
    add2_k<0,true,false><<<1536, 256, 0, stream>>>(refb, projc, nullptr, aob, 393216, 192);
    wsum<<<3072, 256, 0, stream>>>(refb, tkp + (size_t)tq0 * 2, ybuf);
    // final = y @ o_w^T -> d_out, split-K=2: slice0 -> out, slice1 -> t1b
    mgemm<0,false,true,false,0,false,false,true><<<dim3(6,8,2),256,0,stream>>>(
      ybuf, 768, 0LL, o_w, nullptr, 768, 0LL,
      outp + (size_t)tq0 * 768, t1b, 768, 0LL, nullptr, nullptr, 0, 768, 1);
    add2_k<0,false,false><<<768, 256, 0, stream>>>(outp + (size_t)tq0 * 768, t1b, nullptr, nullptr, 196608, 192);
  }
  aux_k<<<1, 64, 0, stream>>>(usage, usage + 8, out_aux);
}